// Round 2
// baseline (2337.943 us; speedup 1.0000x reference)
//
#include <hip/hip_runtime.h>

// QuantizedLinear: out[m][o] = (sum_k x[m][k] * Wint[o][k]) * scale[o] + bias[o]
// M = 4*2048 = 8192, K = 4096, N = 16384.
// Strategy: fold scale into epilogue (exact), GEMM in bf16 MFMA (int8 weights
// are exact in bf16; x bf16-rounding error << threshold).

#define M_DIM 8192
#define N_DIM 16384
#define K_DIM 4096

typedef __attribute__((ext_vector_type(8))) short short8;
typedef __attribute__((ext_vector_type(4))) float f32x4;

__device__ __forceinline__ unsigned short f2bf(float f) {
    unsigned u = __builtin_bit_cast(unsigned, f);
    u += 0x7fffu + ((u >> 16) & 1u);   // round-to-nearest-even
    return (unsigned short)(u >> 16);
}

// ---- conversion kernels (memory-bound, vectorized 16B loads) ----
__global__ void k_cvt_x(const float4* __restrict__ in, ushort4* __restrict__ out, int n4) {
    int stride = gridDim.x * blockDim.x;
    for (int i = blockIdx.x * blockDim.x + threadIdx.x; i < n4; i += stride) {
        float4 v = in[i];
        ushort4 o;
        o.x = f2bf(v.x); o.y = f2bf(v.y); o.z = f2bf(v.z); o.w = f2bf(v.w);
        out[i] = o;
    }
}

__global__ void k_cvt_w(const int4* __restrict__ in, ushort4* __restrict__ out, int n4) {
    int stride = gridDim.x * blockDim.x;
    for (int i = blockIdx.x * blockDim.x + threadIdx.x; i < n4; i += stride) {
        int4 v = in[i];
        ushort4 o;  // ints in [-128,127]: exact in bf16
        o.x = f2bf((float)v.x); o.y = f2bf((float)v.y);
        o.z = f2bf((float)v.z); o.w = f2bf((float)v.w);
        out[i] = o;
    }
}

// ---- GEMM: 128x128 tile, BK=64, 4 waves (2x2), 16x16x32 bf16 MFMA ----
// PRE=true : read pre-converted bf16 A/B via global_load_lds width 16.
// PRE=false: reg-stage raw fp32/int32, convert in-flight, ds_write bf16.
template<bool PRE>
__global__ __launch_bounds__(256)
void k_gemm(const unsigned short* __restrict__ Ab, const unsigned short* __restrict__ Bb,
            const float* __restrict__ Af, const int* __restrict__ Wi,
            const float* __restrict__ scales, const float* __restrict__ bias,
            float* __restrict__ out) {
    __shared__ unsigned short As[128][64];
    __shared__ unsigned short Bs[128][64];

    const int tid  = threadIdx.x;
    const int l    = tid & 63;
    const int w    = tid >> 6;
    const int wrow = w >> 1;          // 0..1
    const int wcol = w & 1;           // 0..1
    const int bM   = blockIdx.y * 128;
    const int bN   = blockIdx.x * 128;

    f32x4 acc[4][4];
#pragma unroll
    for (int m = 0; m < 4; ++m)
#pragma unroll
        for (int n = 0; n < 4; ++n) acc[m][n] = (f32x4)0.0f;

    const int fr = l & 15;            // fragment row within 16
    const int fk = (l >> 4) * 8;      // fragment k-offset within 32-slice

    for (int kt = 0; kt < K_DIM / 64; ++kt) {
        if (PRE) {
            __syncthreads();          // previous compute done reading LDS
#pragma unroll
            for (int i = 0; i < 4; ++i) {
                const int r = w * 32 + i * 8;   // 8 rows per wave-instruction
                const unsigned short* ga = Ab + (size_t)(bM + r + (l >> 3)) * K_DIM
                                              + kt * 64 + (l & 7) * 8;
                __builtin_amdgcn_global_load_lds(
                    (const __attribute__((address_space(1))) void*)ga,
                    (__attribute__((address_space(3))) void*)&As[r][0], 16, 0, 0);
                const unsigned short* gb = Bb + (size_t)(bN + r + (l >> 3)) * K_DIM
                                              + kt * 64 + (l & 7) * 8;
                __builtin_amdgcn_global_load_lds(
                    (const __attribute__((address_space(1))) void*)gb,
                    (__attribute__((address_space(3))) void*)&Bs[r][0], 16, 0, 0);
            }
            __syncthreads();          // vmcnt(0) drain: tiles ready
        } else {
            ushort4 oa[8], ob[8];
#pragma unroll
            for (int p = 0; p < 8; ++p) {
                const int g   = p * 256 + tid;   // float4-granule within 128x64 tile
                const int row = g >> 4;
                const int c4  = g & 15;
                float4 va = ((const float4*)(Af + (size_t)(bM + row) * K_DIM + kt * 64))[c4];
                int4   vb = ((const int4*)  (Wi + (size_t)(bN + row) * K_DIM + kt * 64))[c4];
                oa[p].x = f2bf(va.x); oa[p].y = f2bf(va.y);
                oa[p].z = f2bf(va.z); oa[p].w = f2bf(va.w);
                ob[p].x = f2bf((float)vb.x); ob[p].y = f2bf((float)vb.y);
                ob[p].z = f2bf((float)vb.z); ob[p].w = f2bf((float)vb.w);
            }
            __syncthreads();          // previous compute done reading LDS
#pragma unroll
            for (int p = 0; p < 8; ++p) {
                const int g   = p * 256 + tid;
                const int row = g >> 4;
                const int c4  = g & 15;
                *(ushort4*)&As[row][c4 * 4] = oa[p];
                *(ushort4*)&Bs[row][c4 * 4] = ob[p];
            }
            __syncthreads();          // tiles ready
        }

#pragma unroll
        for (int kk = 0; kk < 2; ++kk) {
            short8 af[4], bf[4];
#pragma unroll
            for (int m = 0; m < 4; ++m)
                af[m] = *(const short8*)&As[wrow * 64 + m * 16 + fr][kk * 32 + fk];
#pragma unroll
            for (int n = 0; n < 4; ++n)
                bf[n] = *(const short8*)&Bs[wcol * 64 + n * 16 + fr][kk * 32 + fk];
#pragma unroll
            for (int m = 0; m < 4; ++m)
#pragma unroll
                for (int n = 0; n < 4; ++n)
                    acc[m][n] = __builtin_amdgcn_mfma_f32_16x16x32_bf16(
                        af[m], bf[n], acc[m][n], 0, 0, 0);
        }
    }

    // epilogue: out = acc * scale[col] + bias[col]
    const int cm = (l >> 4) * 4;      // C/D row base within 16 (m89-verified layout)
#pragma unroll
    for (int n = 0; n < 4; ++n) {
        const int col = bN + wcol * 64 + n * 16 + fr;
        const float s = scales[col];
        const float b = bias[col];
#pragma unroll
        for (int m = 0; m < 4; ++m) {
            const int row0 = bM + wrow * 64 + m * 16 + cm;
#pragma unroll
            for (int r = 0; r < 4; ++r)
                out[(size_t)(row0 + r) * N_DIM + col] = acc[m][n][r] * s + b;
        }
    }
}

extern "C" void kernel_launch(void* const* d_in, const int* in_sizes, int n_in,
                              void* d_out, int out_size, void* d_ws, size_t ws_size,
                              hipStream_t stream) {
    const float* x  = (const float*)d_in[0];
    const int*   wq = (const int*)d_in[1];
    const float* sc = (const float*)d_in[2];
    const float* bi = (const float*)d_in[3];
    float* out = (float*)d_out;

    const size_t needA = (size_t)M_DIM * K_DIM * 2;   // 64 MiB bf16 X
    const size_t needB = (size_t)N_DIM * K_DIM * 2;   // 128 MiB bf16 W
    dim3 grid(N_DIM / 128, M_DIM / 128);

    if (ws_size >= needA + needB) {
        unsigned short* Axb = (unsigned short*)d_ws;
        unsigned short* Wxb = (unsigned short*)((char*)d_ws + needA);
        k_cvt_x<<<2048, 256, 0, stream>>>((const float4*)x, (ushort4*)Axb, M_DIM * K_DIM / 4);
        k_cvt_w<<<2048, 256, 0, stream>>>((const int4*)wq, (ushort4*)Wxb, N_DIM * K_DIM / 4);
        k_gemm<true><<<grid, 256, 0, stream>>>(Axb, Wxb, nullptr, nullptr, sc, bi, out);
    } else {
        k_gemm<false><<<grid, 256, 0, stream>>>(nullptr, nullptr, x, wq, sc, bi, out);
    }
}